// Round 2
// baseline (29597.382 us; speedup 1.0000x reference)
//
#include <hip/hip_runtime.h>
#include <hip/hip_bf16.h>
#include <math.h>

#define BATCH 128
#define SEQ   512
#define IND   512
#define F     1024
#define OUTD  256
// concat K = F + IND = 1536
#define KC    1536
#define N3    3072

typedef __bf16 v8bf __attribute__((ext_vector_type(8)));
typedef float  v4f  __attribute__((ext_vector_type(4)));
typedef unsigned short u16;
typedef u16 v8u __attribute__((ext_vector_type(8)));

__device__ inline u16 f2bf(float x) {
    union { float f; unsigned u; } v; v.f = x;
    unsigned r = v.u + 0x7fff + ((v.u >> 16) & 1);
    return (u16)(r >> 16);
}
__device__ inline float bf2f(u16 h) {
    union { unsigned u; float f; } v; v.u = ((unsigned)h) << 16;
    return v.f;
}

__device__ inline float sigm(float x) { return 1.f / (1.f + __expf(-x)); }
__device__ inline float tanh_fast(float x) {
    float xc = fminf(fmaxf(x, -15.f), 15.f);
    float e = __expf(2.f * xc);
    return (e - 1.f) / (e + 1.f);
}

// ---------------- prep: inputs [B][T][I] fp32 -> x hi/lo planes [T][B][I] bf16 ----------------
__global__ void k_prep_x(const float* __restrict__ in, u16* __restrict__ xhi,
                         u16* __restrict__ xlo) {
    int gid = blockIdx.x * 256 + threadIdx.x;     // 4,194,304 chunks of 8
    int b = gid >> 15;
    int rem = gid & 32767;
    int t = rem >> 6;
    int c = rem & 63;
    const float* s = in + (size_t)gid * 8;
    float4 a0 = ((const float4*)s)[0];
    float4 a1 = ((const float4*)s)[1];
    float a[8] = {a0.x, a0.y, a0.z, a0.w, a1.x, a1.y, a1.z, a1.w};
    v8u oh, ol;
    #pragma unroll
    for (int i = 0; i < 8; i++) {
        u16 h = f2bf(a[i]);
        oh[i] = h;
        ol[i] = f2bf(a[i] - bf2f(h));
    }
    size_t off = (size_t)(t * BATCH + b) * IND + c * 8;
    *(v8u*)(xhi + off) = oh;
    *(v8u*)(xlo + off) = ol;
}

// ------------- prep: WcT[n][k] hi/lo bf16 planes, n in [0,3072), k in [0,1536) --------------
// Wc[k][n] = (k < F) ? Wh[k][n] : Wi[k-F][n]   (tiled transpose via LDS)
__global__ void k_prep_w(const float* __restrict__ Wi, const float* __restrict__ Wh,
                         u16* __restrict__ Whi, u16* __restrict__ Wlo) {
    __shared__ float lds[32][33];
    int nb = blockIdx.x % 96;      // 3072/32
    int kb = blockIdx.x / 96;      // 1536/32
    int tid = threadIdx.x;
    int n_l = tid & 31, kr = tid >> 5;
    #pragma unroll
    for (int j = 0; j < 4; j++) {
        int k_l = kr + j * 8;
        int k = kb * 32 + k_l, n = nb * 32 + n_l;
        float v = (k < F) ? Wh[(size_t)k * N3 + n] : Wi[(size_t)(k - F) * N3 + n];
        lds[k_l][n_l] = v;
    }
    __syncthreads();
    int k_l2 = tid & 31, nr = tid >> 5;
    #pragma unroll
    for (int j = 0; j < 4; j++) {
        int n_l2 = nr + j * 8;
        float v = lds[k_l2][n_l2];
        u16 h = f2bf(v);
        size_t off = (size_t)(nb * 32 + n_l2) * KC + kb * 32 + k_l2;
        Whi[off] = h;
        Wlo[off] = f2bf(v - bf2f(h));
    }
}

// ---------------- persistent GRU recurrence, bf16x2 split precision ----------------
// grid = 256 = 4 batch-groups (gb, Mb=32) x 64 feature-groups (gn, Fb=16)
// block = 256 (4 waves). Every wave: 4 x-chunks (j=0..3, no h dep) then 8 h-chunks.
// Weights (hi+lo) held in VGPRs: 72 v8bf frags = 288 VGPRs/lane.
__launch_bounds__(256, 1)
__global__ void k_gru(const u16* __restrict__ xhi, const u16* __restrict__ xlo,
                      const u16* __restrict__ Whi, const u16* __restrict__ Wlo,
                      u16* __restrict__ hb,           // [2 parity][2 plane][128][1024] bf16
                      unsigned* __restrict__ flags,   // [SEQ][4]
                      const float* __restrict__ bi, const float* __restrict__ bhn,
                      float* __restrict__ dout) {
    __shared__ float accL[2048];   // 8 tiles (4 gate-types x 2 mt) x 256
    const int tid = threadIdx.x;
    const int w = tid >> 6, l = tid & 63;
    const int gb = blockIdx.x >> 6, gn = blockIdx.x & 63;
    const int l15 = l & 15, q = l >> 4;

    // per-wave kk schedule: j<4 -> x chunk (kk=32+w*4+j), j>=4 -> h chunk (kk=w*8+j-4)
    int kklist[12];
    #pragma unroll
    for (int j = 0; j < 12; j++)
        kklist[j] = (j < 4) ? (32 + w * 4 + j) : (w * 8 + (j - 4));

    // weight preload (hi+lo): wreg[j][g], g=0:r 1:z 2:(n, h-part or x-part)
    v8bf wregh[12][3], wregl[12][3];
    #pragma unroll
    for (int j = 0; j < 12; j++) {
        int kk = kklist[j];
        #pragma unroll
        for (int g = 0; g < 3; g++) {
            size_t off = (size_t)(g * F + gn * 16 + l15) * KC + kk * 32 + q * 8;
            wregh[j][g] = *(const v8bf*)(Whi + off);
            wregl[j][g] = *(const v8bf*)(Wlo + off);
        }
    }

    for (int i = tid; i < 2048; i += 256) accL[i] = 0.f;
    __syncthreads();

    // persistent h in fp32 registers: elem0 = (bl0, fl0) in mt0, elem1 = +16 rows (mt1)
    float hp0 = 0.f, hp1 = 0.f;
    const int bl0 = tid >> 4;        // 0..15
    const int fl0 = tid & 15;
    const int fg = gn * 16 + fl0;
    const float bir = bi[fg], biz = bi[F + fg], bin = bi[2 * F + fg], bhnv = bhn[fg];
    const size_t rowA0 = (size_t)(gb * 32 + l15);
    const size_t rowA1 = (size_t)(gb * 32 + 16 + l15);
    const int HP = BATCH * F;        // plane stride; parity stride = 2*HP

    for (int t = 0; t < SEQ; t++) {
        const u16* hsh = hb + (size_t)((t & 1) ^ 1) * (2 * HP);
        const u16* hsl = hsh + HP;
        u16* hdh = hb + (size_t)(t & 1) * (2 * HP);
        u16* hdl = hdh + HP;
        v4f acc[4][2];
        #pragma unroll
        for (int gi = 0; gi < 4; gi++)
            #pragma unroll
            for (int mt = 0; mt < 2; mt++) {
                acc[gi][mt][0] = 0.f; acc[gi][mt][1] = 0.f;
                acc[gi][mt][2] = 0.f; acc[gi][mt][3] = 0.f;
            }

        #pragma unroll
        for (int j = 0; j < 12; j++) {
            int kk = kklist[j];
            if (t > 0 && j == 4) {          // spin after the x-chunks, before h reads
                unsigned* fp = flags + (size_t)(t - 1) * 4 + gb;
                long guard = 0;
                while (__hip_atomic_load(fp, __ATOMIC_RELAXED, __HIP_MEMORY_SCOPE_AGENT) < 64u) {
                    __builtin_amdgcn_s_sleep(1);
                    if (++guard > 400000000L) break;
                }
                __threadfence();
            }
            bool isx = (j < 4);
            if (t == 0 && !isx) continue;   // h(-1) == 0, skip
            v8bf a0h, a1h, a0l, a1l;
            if (isx) {
                size_t base = (size_t)t * (BATCH * IND) + (kk - 32) * 32 + q * 8;
                a0h = *(const v8bf*)(xhi + base + rowA0 * IND);
                a1h = *(const v8bf*)(xhi + base + rowA1 * IND);
                a0l = *(const v8bf*)(xlo + base + rowA0 * IND);
                a1l = *(const v8bf*)(xlo + base + rowA1 * IND);
            } else {
                size_t base = (size_t)kk * 32 + q * 8;
                a0h = *(const v8bf*)(hsh + base + rowA0 * F);
                a1h = *(const v8bf*)(hsh + base + rowA1 * F);
                a0l = *(const v8bf*)(hsl + base + rowA0 * F);
                a1l = *(const v8bf*)(hsl + base + rowA1 * F);
            }
            int g2 = isx ? 3 : 2;
            // r gate
            acc[0][0] = __builtin_amdgcn_mfma_f32_16x16x32_bf16(a0h, wregh[j][0], acc[0][0], 0, 0, 0);
            acc[0][1] = __builtin_amdgcn_mfma_f32_16x16x32_bf16(a1h, wregh[j][0], acc[0][1], 0, 0, 0);
            acc[1][0] = __builtin_amdgcn_mfma_f32_16x16x32_bf16(a0h, wregh[j][1], acc[1][0], 0, 0, 0);
            acc[1][1] = __builtin_amdgcn_mfma_f32_16x16x32_bf16(a1h, wregh[j][1], acc[1][1], 0, 0, 0);
            acc[g2][0] = __builtin_amdgcn_mfma_f32_16x16x32_bf16(a0h, wregh[j][2], acc[g2][0], 0, 0, 0);
            acc[g2][1] = __builtin_amdgcn_mfma_f32_16x16x32_bf16(a1h, wregh[j][2], acc[g2][1], 0, 0, 0);
            // hi * w_lo
            acc[0][0] = __builtin_amdgcn_mfma_f32_16x16x32_bf16(a0h, wregl[j][0], acc[0][0], 0, 0, 0);
            acc[0][1] = __builtin_amdgcn_mfma_f32_16x16x32_bf16(a1h, wregl[j][0], acc[0][1], 0, 0, 0);
            acc[1][0] = __builtin_amdgcn_mfma_f32_16x16x32_bf16(a0h, wregl[j][1], acc[1][0], 0, 0, 0);
            acc[1][1] = __builtin_amdgcn_mfma_f32_16x16x32_bf16(a1h, wregl[j][1], acc[1][1], 0, 0, 0);
            acc[g2][0] = __builtin_amdgcn_mfma_f32_16x16x32_bf16(a0h, wregl[j][2], acc[g2][0], 0, 0, 0);
            acc[g2][1] = __builtin_amdgcn_mfma_f32_16x16x32_bf16(a1h, wregl[j][2], acc[g2][1], 0, 0, 0);
            // lo * w_hi
            acc[0][0] = __builtin_amdgcn_mfma_f32_16x16x32_bf16(a0l, wregh[j][0], acc[0][0], 0, 0, 0);
            acc[0][1] = __builtin_amdgcn_mfma_f32_16x16x32_bf16(a1l, wregh[j][0], acc[0][1], 0, 0, 0);
            acc[1][0] = __builtin_amdgcn_mfma_f32_16x16x32_bf16(a0l, wregh[j][1], acc[1][0], 0, 0, 0);
            acc[1][1] = __builtin_amdgcn_mfma_f32_16x16x32_bf16(a1l, wregh[j][1], acc[1][1], 0, 0, 0);
            acc[g2][0] = __builtin_amdgcn_mfma_f32_16x16x32_bf16(a0l, wregh[j][2], acc[g2][0], 0, 0, 0);
            acc[g2][1] = __builtin_amdgcn_mfma_f32_16x16x32_bf16(a1l, wregh[j][2], acc[g2][1], 0, 0, 0);
        }

        // cross-wave K-reduce into LDS (zeros guaranteed by previous step's cleanup)
        #pragma unroll
        for (int gi = 0; gi < 4; gi++)
            #pragma unroll
            for (int mt = 0; mt < 2; mt++)
                #pragma unroll
                for (int i = 0; i < 4; i++) {
                    int row = q * 4 + i;
                    atomicAdd(&accL[(gi * 2 + mt) * 256 + row * 16 + l15], acc[gi][mt][i]);
                }
        __syncthreads();

        // fused elementwise (2 elements per thread), re-zero acc words after read
        {
            int off = bl0 * 16 + fl0;
            // elem 0: mt=0
            float pr = accL[0 * 256 + off];
            float pz = accL[2 * 256 + off];
            float ph = accL[4 * 256 + off];
            float px = accL[6 * 256 + off];
            accL[0 * 256 + off] = 0.f; accL[2 * 256 + off] = 0.f;
            accL[4 * 256 + off] = 0.f; accL[6 * 256 + off] = 0.f;
            float r = sigm(pr + bir);
            float z = sigm(pz + biz);
            float n = tanh_fast(px + bin + r * (ph + bhnv));
            float hn0 = (1.f - z) * n + z * hp0;
            hp0 = hn0;
            int rowg0 = gb * 32 + bl0;
            u16 hh0 = f2bf(hn0);
            hdh[(size_t)rowg0 * F + fg] = hh0;
            hdl[(size_t)rowg0 * F + fg] = f2bf(hn0 - bf2f(hh0));
            if (t == SEQ - 1) dout[32768 + (size_t)rowg0 * F + fg] = hn0;
            // elem 1: mt=1
            pr = accL[1 * 256 + off];
            pz = accL[3 * 256 + off];
            ph = accL[5 * 256 + off];
            px = accL[7 * 256 + off];
            accL[1 * 256 + off] = 0.f; accL[3 * 256 + off] = 0.f;
            accL[5 * 256 + off] = 0.f; accL[7 * 256 + off] = 0.f;
            r = sigm(pr + bir);
            z = sigm(pz + biz);
            n = tanh_fast(px + bin + r * (ph + bhnv));
            float hn1 = (1.f - z) * n + z * hp1;
            hp1 = hn1;
            int rowg1 = gb * 32 + 16 + bl0;
            u16 hh1 = f2bf(hn1);
            hdh[(size_t)rowg1 * F + fg] = hh1;
            hdl[(size_t)rowg1 * F + fg] = f2bf(hn1 - bf2f(hh1));
            if (t == SEQ - 1) dout[32768 + (size_t)rowg1 * F + fg] = hn1;
        }
        __threadfence();
        __syncthreads();
        if (tid == 0) atomicAdd(flags + (size_t)t * 4 + gb, 1u);
    }
}

// ---------------- output head: out[b][c] = carry[b] . Wo[:,c] + bo[c] (fp32 exact) ----------------
__global__ void k_head(const float* __restrict__ hf, const float* __restrict__ Wo,
                       const float* __restrict__ bo, float* __restrict__ dout) {
    int b = blockIdx.x, c = threadIdx.x;
    const float* h = hf + (size_t)b * F;
    float s = bo[c];
    #pragma unroll 4
    for (int k = 0; k < F; k++) s += h[k] * Wo[(size_t)k * OUTD + c];
    dout[(size_t)b * OUTD + c] = s;
}

extern "C" void kernel_launch(void* const* d_in, const int* in_sizes, int n_in,
                              void* d_out, int out_size, void* d_ws, size_t ws_size,
                              hipStream_t stream) {
    const float* inputs = (const float*)d_in[0];
    const float* Wi     = (const float*)d_in[1];
    const float* bi     = (const float*)d_in[2];
    const float* Wh     = (const float*)d_in[3];
    const float* bhn    = (const float*)d_in[4];
    const float* Wo     = (const float*)d_in[5];
    const float* bo     = (const float*)d_in[6];
    float* out = (float*)d_out;

    char* ws = (char*)d_ws;
    u16* xhi = (u16*)ws;                                  //  67,108,864 B
    u16* xlo = (u16*)(ws + 67108864);                     //  67,108,864 B
    u16* Whi = (u16*)(ws + 134217728);                    //   9,437,184 B
    u16* Wlo = (u16*)(ws + 143654912);                    //   9,437,184 B
    u16* hbuf = (u16*)(ws + 153092096);                   //   1,048,576 B
    unsigned* flags = (unsigned*)(ws + 154140672);        //       8,192 B

    hipMemsetAsync(flags, 0, (size_t)SEQ * 4 * sizeof(unsigned), stream);

    k_prep_x<<<16384, 256, 0, stream>>>(inputs, xhi, xlo);
    k_prep_w<<<4608, 256, 0, stream>>>(Wi, Wh, Whi, Wlo);
    k_gru<<<256, 256, 0, stream>>>(xhi, xlo, Whi, Wlo, hbuf, flags, bi, bhn, out);
    k_head<<<128, 256, 0, stream>>>(out + (size_t)BATCH * OUTD, Wo, bo, out);
}